// Round 5
// baseline (141.985 us; speedup 1.0000x reference)
//
#include <hip/hip_runtime.h>
#include <math.h>

#define EPS 1e-6f
#define C_CH 64          // channels (fixed by reference)
#define BPS_A 256        // blocks per segment, reduction pass
#define BPS_C 256        // blocks per segment, apply pass

typedef float f32x4 __attribute__((ext_vector_type(4)));  // native vec for builtins

// ---------------------------------------------------------------------------
// Block-level sum-of-squares over one segment slice (forward sweep, unroll-2).
// Writes partial[(seg*BPS_A + bip)][64]. Deterministic, no atomics.
// ---------------------------------------------------------------------------
__device__ __forceinline__ void sumsq_block(
    const float4* __restrict__ feat, int start, int end, int bip,
    float* __restrict__ partial_row)    // -> [64] floats for this block
{
    const int t    = threadIdx.x;
    const int c4   = t & 15;
    const int rsub = t >> 4;

    float4 a0 = make_float4(0.f, 0.f, 0.f, 0.f);
    float4 a1 = make_float4(0.f, 0.f, 0.f, 0.f);

    const int stride = BPS_A * 32;
    for (int row = start + bip * 32 + rsub; row < end; row += stride) {
        float4 v = feat[row * 16 + c4];
        a0.x = fmaf(v.x, v.x, a0.x);
        a0.y = fmaf(v.y, v.y, a0.y);
        a0.z = fmaf(v.z, v.z, a0.z);
        a0.w = fmaf(v.w, v.w, a0.w);
        int row2 = row + 16;
        if (row2 < end) {
            float4 w = feat[row2 * 16 + c4];
            a1.x = fmaf(w.x, w.x, a1.x);
            a1.y = fmaf(w.y, w.y, a1.y);
            a1.z = fmaf(w.z, w.z, a1.z);
            a1.w = fmaf(w.w, w.w, a1.w);
        }
    }
    a0.x += a1.x; a0.y += a1.y; a0.z += a1.z; a0.w += a1.w;

    __shared__ float lds[16][C_CH];
    lds[rsub][4 * c4 + 0] = a0.x;
    lds[rsub][4 * c4 + 1] = a0.y;
    lds[rsub][4 * c4 + 2] = a0.z;
    lds[rsub][4 * c4 + 3] = a0.w;
    __syncthreads();

    if (t < C_CH) {
        float s = 0.f;
        #pragma unroll
        for (int r = 0; r < 16; ++r) s += lds[r][t];
        partial_row[t] = s;
    }
}

// ---------------------------------------------------------------------------
// Block-level finalize + apply over one segment slice (forward sweep).
// Prelude: redundant per-block reduce of the segment's BPS_A partial rows
// (tiny, L2-hot) -> response -> channel mean -> mul[c] in LDS.
// Main: out = feat*mul + beta, float4 unroll-2, NONTEMPORAL stores.
// ---------------------------------------------------------------------------
__device__ __forceinline__ void apply_block(
    const float4* __restrict__ feat,
    const float* __restrict__ partial_seg,   // [BPS_A][64] for this segment
    const float* __restrict__ gamma,
    const float4* __restrict__ beta4,
    f32x4* __restrict__ out,
    int start, int end, int bip)
{
    const int t = threadIdx.x;
    const int c = t & 63;
    const int q = t >> 6;

    __shared__ float red[4][C_CH];
    __shared__ float mulsh[C_CH];

    {
        float s = 0.f;
        const float* p = partial_seg + c;
        for (int b = q; b < BPS_A; b += 4) s += p[b * C_CH];
        red[q][c] = s;
        __syncthreads();
        if (t < C_CH) {
            float tot  = red[0][c] + red[1][c] + red[2][c] + red[3][c];
            float resp = sqrtf(tot);
            float m = resp;
            #pragma unroll
            for (int off = 1; off < 64; off <<= 1) m += __shfl_xor(m, off, 64);
            float mean = m * (1.0f / 64.0f);
            mulsh[c] = 1.0f + gamma[c] * (resp / (mean + EPS));
        }
        __syncthreads();
    }

    const int c4   = t & 15;
    const int rsub = t >> 4;
    const float4 mm = ((const float4*)mulsh)[c4];
    const float4 bt = beta4[c4];

    const int stride = BPS_C * 32;
    for (int row = start + bip * 32 + rsub; row < end; row += stride) {
        float4 v = feat[row * 16 + c4];
        f32x4 o;
        o.x = fmaf(v.x, mm.x, bt.x);
        o.y = fmaf(v.y, mm.y, bt.y);
        o.z = fmaf(v.z, mm.z, bt.z);
        o.w = fmaf(v.w, mm.w, bt.w);
        __builtin_nontemporal_store(o, &out[row * 16 + c4]);
        int row2 = row + 16;
        if (row2 < end) {
            float4 w = feat[row2 * 16 + c4];
            f32x4 o2;
            o2.x = fmaf(w.x, mm.x, bt.x);
            o2.y = fmaf(w.y, mm.y, bt.y);
            o2.z = fmaf(w.z, mm.z, bt.z);
            o2.w = fmaf(w.w, mm.w, bt.w);
            __builtin_nontemporal_store(o2, &out[row2 * 16 + c4]);
        }
    }
}

// ---------------------------------------------------------------------------
// Launch 1: sumsq for segments [segBase, segBase+nSeg)
// ---------------------------------------------------------------------------
__global__ __launch_bounds__(256) void k_sumsq(
    const float4* __restrict__ feat, const int* __restrict__ offset,
    float* __restrict__ partial, int segBase)
{
    const int seg = segBase + blockIdx.x / BPS_A;
    const int bip = blockIdx.x % BPS_A;
    const int start = (seg == 0) ? 0 : offset[seg - 1];
    const int end   = offset[seg];
    sumsq_block(feat, start, end, bip, partial + (seg * BPS_A + bip) * C_CH);
}

// ---------------------------------------------------------------------------
// Launch 2 (mixed): blocks [0, h2*BPS_A) do sumsq for segments [h1, B);
// blocks [h2*BPS_A, ...) do apply for segments [0, h1).
// Apply reads re-hit the L3 lines Launch 1 just filled.
// ---------------------------------------------------------------------------
__global__ __launch_bounds__(256) void k_mixed(
    const float4* __restrict__ feat, const int* __restrict__ offset,
    float* __restrict__ partial, const float* __restrict__ gamma,
    const float4* __restrict__ beta4, f32x4* __restrict__ out,
    int h1)
{
    const int nA = ((int)gridDim.x - h1 * BPS_C);   // = h2*BPS_A
    if ((int)blockIdx.x < nA) {
        const int seg = h1 + blockIdx.x / BPS_A;
        const int bip = blockIdx.x % BPS_A;
        const int start = (seg == 0) ? 0 : offset[seg - 1];
        const int end   = offset[seg];
        sumsq_block(feat, start, end, bip, partial + (seg * BPS_A + bip) * C_CH);
    } else {
        const int lin = blockIdx.x - nA;
        const int seg = lin / BPS_C;                // 0 .. h1-1
        const int bip = lin % BPS_C;
        const int start = (seg == 0) ? 0 : offset[seg - 1];
        const int end   = offset[seg];
        apply_block(feat, partial + seg * BPS_A * C_CH, gamma, beta4, out,
                    start, end, bip);
    }
}

// ---------------------------------------------------------------------------
// Launch 3: apply for segments [segBase, B)
// ---------------------------------------------------------------------------
__global__ __launch_bounds__(256) void k_apply(
    const float4* __restrict__ feat, const int* __restrict__ offset,
    const float* __restrict__ partial, const float* __restrict__ gamma,
    const float4* __restrict__ beta4, f32x4* __restrict__ out, int segBase)
{
    const int seg = segBase + blockIdx.x / BPS_C;
    const int bip = blockIdx.x % BPS_C;
    const int start = (seg == 0) ? 0 : offset[seg - 1];
    const int end   = offset[seg];
    apply_block(feat, partial + seg * BPS_A * C_CH, gamma, beta4, out,
                start, end, bip);
}

// ---------------------------------------------------------------------------
extern "C" void kernel_launch(void* const* d_in, const int* in_sizes, int n_in,
                              void* d_out, int out_size, void* d_ws, size_t ws_size,
                              hipStream_t stream)
{
    const float4* feat   = (const float4*)d_in[0];
    const int*    offset = (const int*)d_in[1];
    const float*  gamma  = (const float*)d_in[2];
    const float4* beta4  = (const float4*)d_in[3];
    f32x4*        out    = (f32x4*)d_out;

    const int B = in_sizes[1];   // number of segments (8)
    float* partial = (float*)d_ws;   // B*BPS_A*64 floats

    const int h1 = B / 2;        // first half (applied in L2)
    const int h2 = B - h1;       // second half

    if (h1 > 0) {
        k_sumsq<<<h1 * BPS_A, 256, 0, stream>>>(feat, offset, partial, 0);
        k_mixed<<<h2 * BPS_A + h1 * BPS_C, 256, 0, stream>>>(
            feat, offset, partial, gamma, beta4, out, h1);
        k_apply<<<h2 * BPS_C, 256, 0, stream>>>(
            feat, offset, partial, gamma, beta4, out, h1);
    } else {
        // B == 1 fallback: plain two-pass
        k_sumsq<<<BPS_A, 256, 0, stream>>>(feat, offset, partial, 0);
        k_apply<<<BPS_C, 256, 0, stream>>>(feat, offset, partial, gamma, beta4,
                                           out, 0);
    }
}